// Round 1
// baseline (579.659 us; speedup 1.0000x reference)
//
#include <hip/hip_runtime.h>
#include <hip/hip_bf16.h>
#include <stdint.h>

// ---------------------------------------------------------------------------
// Transformer block fwd on gfx950. bf16 MFMA for all GEMMs + flash attention.
// B=2 T=2048 C=1024 H=16 HD=64.
// ---------------------------------------------------------------------------

typedef __bf16 bf16x8 __attribute__((ext_vector_type(8)));
typedef __bf16 bf16x4 __attribute__((ext_vector_type(4)));
typedef float  f32x4  __attribute__((ext_vector_type(4)));

#define GLDS16(g, l)                                                          \
  __builtin_amdgcn_global_load_lds(                                           \
      (__attribute__((address_space(1))) void*)(g),                           \
      (__attribute__((address_space(3))) void*)(l), 16, 0, 0)

__device__ __forceinline__ float gelu_f(float x) {
  const float c = 0.7978845608028654f;
  float u = c * (x + 0.044715f * x * x * x);
  return 0.5f * x * (1.0f + tanhf(u));
}

// ---------------------------------------------------------------------------
// cast 4 fp32 weight matrices to bf16 (blockIdx.y selects array)
// ---------------------------------------------------------------------------
__global__ __launch_bounds__(256) void cast_w(
    const float* s0, const float* s1, const float* s2, const float* s3,
    __bf16* d0, __bf16* d1, __bf16* d2, __bf16* d3,
    int n0, int n1, int n2, int n3) {
  int a = blockIdx.y;
  const float* s = (a == 0) ? s0 : (a == 1) ? s1 : (a == 2) ? s2 : s3;
  __bf16* d      = (a == 0) ? d0 : (a == 1) ? d1 : (a == 2) ? d2 : d3;
  int n          = (a == 0) ? n0 : (a == 1) ? n1 : (a == 2) ? n2 : n3;
  int i = (blockIdx.x * 256 + threadIdx.x) * 4;
  if (i < n) {
    float4 v = *(const float4*)(s + i);
    bf16x4 o = {(__bf16)v.x, (__bf16)v.y, (__bf16)v.z, (__bf16)v.w};
    *(bf16x4*)(d + i) = o;
  }
}

// ---------------------------------------------------------------------------
// LayerNorm over C=1024, one block (256 thr) per row; bf16 output
// ---------------------------------------------------------------------------
__global__ __launch_bounds__(256) void ln_kernel(
    const float* __restrict__ x, const float* __restrict__ gw,
    const float* __restrict__ gb, __bf16* __restrict__ out) {
  const int row = blockIdx.x, tid = threadIdx.x;
  const float4 v = ((const float4*)(x + (size_t)row * 1024))[tid];
  float s = v.x + v.y + v.z + v.w;
  float sq = v.x * v.x + v.y * v.y + v.z * v.z + v.w * v.w;
#pragma unroll
  for (int m = 1; m < 64; m <<= 1) {
    s += __shfl_xor(s, m, 64);
    sq += __shfl_xor(sq, m, 64);
  }
  __shared__ float red[8];
  if ((tid & 63) == 0) { red[tid >> 6] = s; red[4 + (tid >> 6)] = sq; }
  __syncthreads();
  s = red[0] + red[1] + red[2] + red[3];
  sq = red[4] + red[5] + red[6] + red[7];
  const float mu = s * (1.0f / 1024.0f);
  const float var = sq * (1.0f / 1024.0f) - mu * mu;
  const float rs = rsqrtf(var + 1e-5f);
  const float4 wv = ((const float4*)gw)[tid];
  const float4 bv = ((const float4*)gb)[tid];
  bf16x4 o;
  o[0] = (__bf16)((v.x - mu) * rs * wv.x + bv.x);
  o[1] = (__bf16)((v.y - mu) * rs * wv.y + bv.y);
  o[2] = (__bf16)((v.z - mu) * rs * wv.z + bv.z);
  o[3] = (__bf16)((v.w - mu) * rs * wv.w + bv.w);
  *(bf16x4*)(out + (size_t)row * 1024 + tid * 4) = o;
}

// ---------------------------------------------------------------------------
// GEMM: C[M,N] = A[M,K] * Bw[N,K]^T (+bias, epilogue). m97 structure:
// 128x128 tile, BK=32, global_load_lds width 16, 4 waves x (4x4) 16x16x32 MFMA
// EPI: 0 = bias -> bf16 out; 1 = bias + fp32 resid -> fp32 out; 2 = bias+gelu -> bf16
// ---------------------------------------------------------------------------
template <int EPI>
__global__ __launch_bounds__(256) void gemm_bt(
    const __bf16* __restrict__ A, const __bf16* __restrict__ Bw,
    const float* __restrict__ bias, const float* __restrict__ resid,
    float* __restrict__ outF, __bf16* __restrict__ outH, int M, int N, int K) {
  __shared__ __bf16 As[128 * 32];
  __shared__ __bf16 Bs[128 * 32];
  const int tid = threadIdx.x;
  const int w = tid >> 6, lane = tid & 63, l15 = lane & 15, quad = lane >> 4;
  const int wm = (w >> 1) * 64, wn = (w & 1) * 64;
  const int m0 = blockIdx.y * 128, n0 = blockIdx.x * 128;
  const int arow = tid >> 2, acol = (tid & 3) * 8;

  f32x4 acc[4][4] = {};

  const __bf16* ga = A + (size_t)(m0 + arow) * K + acol;
  const __bf16* gb = Bw + (size_t)(n0 + arow) * K + acol;
  for (int k0 = 0; k0 < K; k0 += 32) {
    __syncthreads();
    GLDS16(ga + k0, (char*)As + tid * 16);
    GLDS16(ga + k0 + (size_t)64 * K, (char*)As + 4096 + tid * 16);
    GLDS16(gb + k0, (char*)Bs + tid * 16);
    GLDS16(gb + k0 + (size_t)64 * K, (char*)Bs + 4096 + tid * 16);
    __syncthreads();
    bf16x8 af[4], bfr[4];
#pragma unroll
    for (int i = 0; i < 4; ++i)
      af[i] = *(const bf16x8*)(As + (wm + i * 16 + l15) * 32 + quad * 8);
#pragma unroll
    for (int j = 0; j < 4; ++j)
      bfr[j] = *(const bf16x8*)(Bs + (wn + j * 16 + l15) * 32 + quad * 8);
#pragma unroll
    for (int i = 0; i < 4; ++i)
#pragma unroll
      for (int j = 0; j < 4; ++j)
        acc[i][j] = __builtin_amdgcn_mfma_f32_16x16x32_bf16(af[i], bfr[j],
                                                            acc[i][j], 0, 0, 0);
  }
  // epilogue: D layout col=lane&15, row=quad*4+r
#pragma unroll
  for (int j = 0; j < 4; ++j) {
    const int n = n0 + wn + j * 16 + l15;
    const float bv = bias[n];
#pragma unroll
    for (int i = 0; i < 4; ++i) {
      const int mrow = m0 + wm + i * 16 + quad * 4;
#pragma unroll
      for (int r = 0; r < 4; ++r) {
        const size_t idx = (size_t)(mrow + r) * N + n;
        float v = acc[i][j][r] + bv;
        if (EPI == 0) {
          outH[idx] = (__bf16)v;
        } else if (EPI == 1) {
          outF[idx] = v + resid[idx];
        } else {
          outH[idx] = (__bf16)gelu_f(v);
        }
      }
    }
  }
}

// ---------------------------------------------------------------------------
// Flash attention w/ online softmax + entropy. qkv (B,T,3C) bf16.
// Block: 64 Q rows (4 waves x 16), K-tiles of 64, HD=64.
// Entropy per row: H = m + ln(l) - r/l, r = sum e_i * s_i (online-rescaled).
// ---------------------------------------------------------------------------
__global__ __launch_bounds__(256) void attn_kernel(
    const __bf16* __restrict__ qkv, __bf16* __restrict__ attn_out,
    float* __restrict__ ent_acc) {
  const int qt = blockIdx.x;   // 0..31 (q tile of 64)
  const int bh = blockIdx.y;   // 0..31
  const int b = bh >> 4, h = bh & 15;
  const int tid = threadIdx.x, w = tid >> 6, lane = tid & 63;
  const int l15 = lane & 15, quad = lane >> 4;
  const int q0 = qt * 64;

  __shared__ __bf16 Qs[64 * 64];
  __shared__ __bf16 Ks[64 * 64];
  __shared__ __bf16 Vt[64 * 64];       // transposed: Vt[d][key]
  __shared__ __bf16 Ps[4][16 * 72];    // per-wave P, stride 72 (16B aligned)
  __shared__ float entred[4];

  const __bf16* qbase = qkv + ((size_t)(b * 2048 + q0)) * 3072 + h * 64;
  const __bf16* kbase = qkv + (size_t)(b * 2048) * 3072 + 1024 + h * 64;
  const __bf16* vbase = qkv + (size_t)(b * 2048) * 3072 + 2048 + h * 64;

  {
    const int row = tid >> 3, col = (tid & 7) * 8;
    GLDS16(qbase + (size_t)row * 3072 + col, (char*)Qs + tid * 16);
    GLDS16(qbase + (size_t)(row + 32) * 3072 + col, (char*)Qs + 4096 + tid * 16);
  }

  f32x4 O[4] = {};
  float m_r[4], l_r[4], r_r[4];
#pragma unroll
  for (int r = 0; r < 4; ++r) { m_r[r] = -1e30f; l_r[r] = 0.f; r_r[r] = 0.f; }

  for (int kt = 0; kt <= qt; ++kt) {
    const int kk0 = kt * 64;
    __syncthreads();
    {
      const int row = tid >> 3, col = (tid & 7) * 8;
      GLDS16(kbase + (size_t)(kk0 + row) * 3072 + col, (char*)Ks + tid * 16);
      GLDS16(kbase + (size_t)(kk0 + row + 32) * 3072 + col,
             (char*)Ks + 4096 + tid * 16);
    }
    // V transposed into LDS: lane=key row, wave picks d-chunk (2 rounds)
#pragma unroll
    for (int rd = 0; rd < 2; ++rd) {
      const int d0 = w * 8 + rd * 32;
      bf16x8 vv = *(const bf16x8*)(vbase + (size_t)(kk0 + lane) * 3072 + d0);
#pragma unroll
      for (int i = 0; i < 8; ++i) Vt[(d0 + i) * 64 + lane] = vv[i];
    }
    __syncthreads();

    // S = Q K^T for this wave's 16 q-rows x 64 keys
    f32x4 sacc[4] = {};
#pragma unroll
    for (int s = 0; s < 2; ++s) {
      bf16x8 aq = *(const bf16x8*)(Qs + (w * 16 + l15) * 64 + s * 32 + quad * 8);
#pragma unroll
      for (int jt = 0; jt < 4; ++jt) {
        bf16x8 bk =
            *(const bf16x8*)(Ks + (jt * 16 + l15) * 64 + s * 32 + quad * 8);
        sacc[jt] = __builtin_amdgcn_mfma_f32_16x16x32_bf16(aq, bk, sacc[jt], 0, 0, 0);
      }
    }
    // scale + causal mask
    float sv[4][4];
    const int qrow_g = q0 + w * 16 + quad * 4;
#pragma unroll
    for (int jt = 0; jt < 4; ++jt)
#pragma unroll
      for (int r = 0; r < 4; ++r) {
        float xv = sacc[jt][r] * 0.125f;
        const int kc = kk0 + jt * 16 + l15;
        if (kc > qrow_g + r) xv = -1e30f;
        sv[jt][r] = xv;
      }
    // online softmax update
    float al[4], ev[4][4];
#pragma unroll
    for (int r = 0; r < 4; ++r) {
      float v = fmaxf(fmaxf(sv[0][r], sv[1][r]), fmaxf(sv[2][r], sv[3][r]));
      v = fmaxf(v, __shfl_xor(v, 1, 16));
      v = fmaxf(v, __shfl_xor(v, 2, 16));
      v = fmaxf(v, __shfl_xor(v, 4, 16));
      v = fmaxf(v, __shfl_xor(v, 8, 16));
      const float mn = fmaxf(m_r[r], v);
      al[r] = __expf(m_r[r] - mn);
      m_r[r] = mn;
      float ls = 0.f, rs2 = 0.f;
#pragma unroll
      for (int jt = 0; jt < 4; ++jt) {
        const float e = __expf(sv[jt][r] - mn);
        ev[jt][r] = e;
        ls += e;
        rs2 += e * sv[jt][r];
      }
      ls += __shfl_xor(ls, 1, 16);  rs2 += __shfl_xor(rs2, 1, 16);
      ls += __shfl_xor(ls, 2, 16);  rs2 += __shfl_xor(rs2, 2, 16);
      ls += __shfl_xor(ls, 4, 16);  rs2 += __shfl_xor(rs2, 4, 16);
      ls += __shfl_xor(ls, 8, 16);  rs2 += __shfl_xor(rs2, 8, 16);
      l_r[r] = l_r[r] * al[r] + ls;
      r_r[r] = r_r[r] * al[r] + rs2;
    }
#pragma unroll
    for (int jt = 0; jt < 4; ++jt)
#pragma unroll
      for (int r = 0; r < 4; ++r) O[jt][r] *= al[r];
    // P (C-layout) -> LDS -> A-layout for PV
    __bf16* prow = Ps[w];
#pragma unroll
    for (int jt = 0; jt < 4; ++jt)
#pragma unroll
      for (int r = 0; r < 4; ++r)
        prow[(quad * 4 + r) * 72 + jt * 16 + l15] = (__bf16)ev[jt][r];
    asm volatile("s_waitcnt lgkmcnt(0)" ::: "memory");
#pragma unroll
    for (int s = 0; s < 2; ++s) {
      bf16x8 ap = *(const bf16x8*)(prow + l15 * 72 + s * 32 + quad * 8);
#pragma unroll
      for (int jt = 0; jt < 4; ++jt) {
        bf16x8 bv =
            *(const bf16x8*)(Vt + (jt * 16 + l15) * 64 + s * 32 + quad * 8);
        O[jt] = __builtin_amdgcn_mfma_f32_16x16x32_bf16(ap, bv, O[jt], 0, 0, 0);
      }
    }
  }

  // finalize: O/l -> attn_out (bf16, (B,T,C) with c = h*64+d)
  float inv_l[4];
#pragma unroll
  for (int r = 0; r < 4; ++r) inv_l[r] = 1.0f / l_r[r];
  __bf16* obase = attn_out + (size_t)(b * 2048 + q0 + w * 16) * 1024 + h * 64;
#pragma unroll
  for (int jt = 0; jt < 4; ++jt)
#pragma unroll
    for (int r = 0; r < 4; ++r)
      obase[(size_t)(quad * 4 + r) * 1024 + jt * 16 + l15] =
          (__bf16)(O[jt][r] * inv_l[r]);

  // entropy: per-lane sum over its quad's 4 rows (replicated across 16 lanes)
  float hsum = 0.f;
#pragma unroll
  for (int r = 0; r < 4; ++r)
    hsum += m_r[r] + logf(l_r[r]) - r_r[r] * inv_l[r];
  hsum += __shfl_xor(hsum, 16, 64);
  hsum += __shfl_xor(hsum, 32, 64);
  if (lane == 0) entred[w] = hsum;
  __syncthreads();
  if (tid == 0)
    atomicAdd(ent_acc,
              (entred[0] + entred[1] + entred[2] + entred[3]) * (1.0f / 65536.0f));
}

// ---------------------------------------------------------------------------
// present = stack([k,v]) -> (2,B,H,T,HD) fp32 (d_out region is 4B-aligned only)
// ---------------------------------------------------------------------------
__global__ __launch_bounds__(256) void present_kernel(
    const __bf16* __restrict__ qkv, float* __restrict__ pres) {
  const int e = blockIdx.x * 256 + threadIdx.x;  // vec4 index over 2*B*H*T*16
  const int d4 = e & 15;
  const int t = (e >> 4) & 2047;
  const int hh = (e >> 15) & 15;
  const int b = (e >> 19) & 1;
  const int kv = (e >> 20) & 1;
  bf16x4 vv = *(const bf16x4*)(qkv + (size_t)(b * 2048 + t) * 3072 +
                               (size_t)(1 + kv) * 1024 + hh * 64 + d4 * 4);
  float* po = pres + (size_t)(((kv * 2 + b) * 16 + hh) * 2048 + t) * 64 + d4 * 4;
  po[0] = (float)vv[0];
  po[1] = (float)vv[1];
  po[2] = (float)vv[2];
  po[3] = (float)vv[3];
}

__global__ void ent_final(const float* __restrict__ e, float* __restrict__ o) {
  if (threadIdx.x == 0) o[0] = e[0];
}

// ---------------------------------------------------------------------------
extern "C" void kernel_launch(void* const* d_in, const int* in_sizes, int n_in,
                              void* d_out, int out_size, void* d_ws,
                              size_t ws_size, hipStream_t stream) {
  const float* x      = (const float*)d_in[0];
  const float* ln1_w  = (const float*)d_in[1];
  const float* ln1_b  = (const float*)d_in[2];
  const float* w_attn = (const float*)d_in[3];
  const float* b_attn = (const float*)d_in[4];
  const float* w_proj = (const float*)d_in[5];
  const float* b_proj = (const float*)d_in[6];
  const float* ln2_w  = (const float*)d_in[7];
  const float* ln2_b  = (const float*)d_in[8];
  const float* w_fc   = (const float*)d_in[9];
  const float* b_fc   = (const float*)d_in[10];
  const float* w_mlp  = (const float*)d_in[11];
  const float* b_mlp  = (const float*)d_in[12];

  char* ws = (char*)d_ws;
  constexpr size_t MB = 1024ull * 1024ull;
  // layout (lifetimes): act [0,32MB) overlaps qkv/wb_attn/wb_proj (all dead
  // before the FC GEMM writes act)
  __bf16* qkv    = (__bf16*)(ws + 0);        // (B*T,3C) live: qkv-gemm..attn
  __bf16* act    = (__bf16*)(ws + 0);        // (B*T,4C) live: fc..mlp
  __bf16* wbattn = (__bf16*)(ws + 24 * MB);  // live: qkv-gemm
  __bf16* wbproj = (__bf16*)(ws + 30 * MB);  // live: proj-gemm
  __bf16* attnb  = (__bf16*)(ws + 32 * MB);  // attn out, live: attn..proj
  __bf16* hb     = (__bf16*)(ws + 40 * MB);  // h1 then h2
  float*  x2     = (float*)(ws + 48 * MB);   // x + attn branch (fp32)
  __bf16* wbfc   = (__bf16*)(ws + 64 * MB);
  __bf16* wbmlp  = (__bf16*)(ws + 72 * MB);
  float*  entw   = (float*)(ws + 80 * MB);

  float* xout   = (float*)d_out;
  float* entout = xout + 4194304;
  float* pres   = xout + 4194305;

  hipMemsetAsync(entw, 0, sizeof(float), stream);
  cast_w<<<dim3(4096, 4), 256, 0, stream>>>(
      w_attn, w_proj, w_fc, w_mlp, wbattn, wbproj, wbfc, wbmlp,
      3 * 1024 * 1024, 1024 * 1024, 4 * 1024 * 1024, 4 * 1024 * 1024);
  ln_kernel<<<4096, 256, 0, stream>>>(x, ln1_w, ln1_b, hb);
  gemm_bt<0><<<dim3(24, 32), 256, 0, stream>>>(hb, wbattn, b_attn, nullptr,
                                               nullptr, qkv, 4096, 3072, 1024);
  present_kernel<<<8192, 256, 0, stream>>>(qkv, pres);
  attn_kernel<<<dim3(32, 32), 256, 0, stream>>>(qkv, attnb, entw);
  gemm_bt<1><<<dim3(8, 32), 256, 0, stream>>>(attnb, wbproj, b_proj, x, x2,
                                              nullptr, 4096, 1024, 1024);
  ln_kernel<<<4096, 256, 0, stream>>>(x2, ln2_w, ln2_b, hb);
  gemm_bt<2><<<dim3(32, 32), 256, 0, stream>>>(hb, wbfc, b_fc, nullptr, nullptr,
                                               act, 4096, 4096, 1024);
  gemm_bt<1><<<dim3(8, 32), 256, 0, stream>>>(act, wbmlp, b_mlp, x2, xout,
                                              nullptr, 4096, 1024, 4096);
  ent_final<<<1, 64, 0, stream>>>(entw, entout);
}

// Round 2
// 429.749 us; speedup vs baseline: 1.3488x; 1.3488x over previous
//
#include <hip/hip_runtime.h>
#include <hip/hip_bf16.h>
#include <stdint.h>

// ---------------------------------------------------------------------------
// Transformer block fwd on gfx950. bf16 MFMA GEMMs + S^T-layout flash attn.
// B=2 T=2048 C=1024 H=16 HD=64.
// ---------------------------------------------------------------------------

typedef __bf16 bf16x8 __attribute__((ext_vector_type(8)));
typedef __bf16 bf16x4 __attribute__((ext_vector_type(4)));
typedef float  f32x4  __attribute__((ext_vector_type(4)));

#define GLDS16(g, l)                                                          \
  __builtin_amdgcn_global_load_lds(                                           \
      (__attribute__((address_space(1))) void*)(g),                           \
      (__attribute__((address_space(3))) void*)(l), 16, 0, 0)

__device__ __forceinline__ float gelu_f(float x) {
  const float c = 0.7978845608028654f;
  float u = c * (x + 0.044715f * x * x * x);
  return 0.5f * x * (1.0f + tanhf(u));
}

// ---------------------------------------------------------------------------
// cast 4 fp32 weight matrices to bf16 (blockIdx.y selects array)
// ---------------------------------------------------------------------------
__global__ __launch_bounds__(256) void cast_w(
    const float* s0, const float* s1, const float* s2, const float* s3,
    __bf16* d0, __bf16* d1, __bf16* d2, __bf16* d3,
    int n0, int n1, int n2, int n3) {
  int a = blockIdx.y;
  const float* s = (a == 0) ? s0 : (a == 1) ? s1 : (a == 2) ? s2 : s3;
  __bf16* d      = (a == 0) ? d0 : (a == 1) ? d1 : (a == 2) ? d2 : d3;
  int n          = (a == 0) ? n0 : (a == 1) ? n1 : (a == 2) ? n2 : n3;
  int i = (blockIdx.x * 256 + threadIdx.x) * 4;
  if (i < n) {
    float4 v = *(const float4*)(s + i);
    bf16x4 o = {(__bf16)v.x, (__bf16)v.y, (__bf16)v.z, (__bf16)v.w};
    *(bf16x4*)(d + i) = o;
  }
}

// ---------------------------------------------------------------------------
// LayerNorm over C=1024, one block (256 thr) per row; bf16 output
// ---------------------------------------------------------------------------
__global__ __launch_bounds__(256) void ln_kernel(
    const float* __restrict__ x, const float* __restrict__ gw,
    const float* __restrict__ gb, __bf16* __restrict__ out) {
  const int row = blockIdx.x, tid = threadIdx.x;
  const float4 v = ((const float4*)(x + (size_t)row * 1024))[tid];
  float s = v.x + v.y + v.z + v.w;
  float sq = v.x * v.x + v.y * v.y + v.z * v.z + v.w * v.w;
#pragma unroll
  for (int m = 1; m < 64; m <<= 1) {
    s += __shfl_xor(s, m, 64);
    sq += __shfl_xor(sq, m, 64);
  }
  __shared__ float red[8];
  if ((tid & 63) == 0) { red[tid >> 6] = s; red[4 + (tid >> 6)] = sq; }
  __syncthreads();
  s = red[0] + red[1] + red[2] + red[3];
  sq = red[4] + red[5] + red[6] + red[7];
  const float mu = s * (1.0f / 1024.0f);
  const float var = sq * (1.0f / 1024.0f) - mu * mu;
  const float rs = rsqrtf(var + 1e-5f);
  const float4 wv = ((const float4*)gw)[tid];
  const float4 bv = ((const float4*)gb)[tid];
  bf16x4 o;
  o[0] = (__bf16)((v.x - mu) * rs * wv.x + bv.x);
  o[1] = (__bf16)((v.y - mu) * rs * wv.y + bv.y);
  o[2] = (__bf16)((v.z - mu) * rs * wv.z + bv.z);
  o[3] = (__bf16)((v.w - mu) * rs * wv.w + bv.w);
  *(bf16x4*)(out + (size_t)row * 1024 + tid * 4) = o;
}

// ---------------------------------------------------------------------------
// GEMM: C[M,N] = A[M,K] * Bw[N,K]^T (+bias, epilogue). m97 structure:
// 128xBN tile, BK=32, global_load_lds width 16, 4 waves MFMA 16x16x32.
// EPI: 0 = bias -> bf16; 1 = bias + fp32 resid -> fp32; 2 = bias+gelu -> bf16
// BN: 128 (big-N gemms) or 64 (N=1024 gemms -> 512-block grid)
// ---------------------------------------------------------------------------
template <int EPI, int BN>
__global__ __launch_bounds__(256) void gemm_bt(
    const __bf16* __restrict__ A, const __bf16* __restrict__ Bw,
    const float* __restrict__ bias, const float* __restrict__ resid,
    float* __restrict__ outF, __bf16* __restrict__ outH, int M, int N, int K) {
  __shared__ __bf16 As[128 * 32];
  __shared__ __bf16 Bs[BN * 32];
  constexpr int JN = BN / 32;  // n-subtiles per wave
  const int tid = threadIdx.x;
  const int w = tid >> 6, lane = tid & 63, l15 = lane & 15, quad = lane >> 4;
  const int wm = (w >> 1) * 64, wn = (w & 1) * (BN / 2);
  const int m0 = blockIdx.y * 128, n0 = blockIdx.x * BN;
  const int arow = tid >> 2, acol = (tid & 3) * 8;

  f32x4 acc[4][JN] = {};

  const __bf16* ga = A + (size_t)(m0 + arow) * K + acol;
  const __bf16* gb = Bw + (size_t)(n0 + arow) * K + acol;
  for (int k0 = 0; k0 < K; k0 += 32) {
    __syncthreads();
    GLDS16(ga + k0, (char*)As + tid * 16);
    GLDS16(ga + k0 + (size_t)64 * K, (char*)As + 4096 + tid * 16);
    GLDS16(gb + k0, (char*)Bs + tid * 16);
    if (BN == 128)
      GLDS16(gb + k0 + (size_t)64 * K, (char*)Bs + 4096 + tid * 16);
    __syncthreads();
    bf16x8 af[4], bfr[JN];
#pragma unroll
    for (int i = 0; i < 4; ++i)
      af[i] = *(const bf16x8*)(As + (wm + i * 16 + l15) * 32 + quad * 8);
#pragma unroll
    for (int j = 0; j < JN; ++j)
      bfr[j] = *(const bf16x8*)(Bs + (wn + j * 16 + l15) * 32 + quad * 8);
#pragma unroll
    for (int i = 0; i < 4; ++i)
#pragma unroll
      for (int j = 0; j < JN; ++j)
        acc[i][j] = __builtin_amdgcn_mfma_f32_16x16x32_bf16(af[i], bfr[j],
                                                            acc[i][j], 0, 0, 0);
  }
  // epilogue: D layout col=lane&15 (=n), row=quad*4+r (=m)
#pragma unroll
  for (int j = 0; j < JN; ++j) {
    const int n = n0 + wn + j * 16 + l15;
    const float bv = bias[n];
#pragma unroll
    for (int i = 0; i < 4; ++i) {
      const int mrow = m0 + wm + i * 16 + quad * 4;
#pragma unroll
      for (int r = 0; r < 4; ++r) {
        const size_t idx = (size_t)(mrow + r) * N + n;
        float v = acc[i][j][r] + bv;
        if (EPI == 0) {
          outH[idx] = (__bf16)v;
        } else if (EPI == 1) {
          outF[idx] = v + resid[idx];
        } else {
          outH[idx] = (__bf16)gelu_f(v);
        }
      }
    }
  }
}

// ---------------------------------------------------------------------------
// prep: from qkv (B,T,3C) bf16 produce
//   Qb,Kb : (B,H,T,64) bf16 (contiguous per-head rows)
//   Vtb   : (B,H,64,T) bf16 (pre-transposed V)
//   pres  : (2,B,H,T,64) fp32 (the `present` output)
// One block per (bh, t-tile of 64).
// ---------------------------------------------------------------------------
__global__ __launch_bounds__(256) void prep_kernel(
    const __bf16* __restrict__ qkv, __bf16* __restrict__ Qb,
    __bf16* __restrict__ Kb, __bf16* __restrict__ Vtb,
    float* __restrict__ pres) {
  const int tt = blockIdx.x, bh = blockIdx.y;
  const int b = bh >> 4, h = bh & 15;
  const int t0 = tt * 64, tid = threadIdx.x;
  const int r = tid >> 2, c = (tid & 3) * 16;
  __shared__ __bf16 Vs[64 * 72];

  const __bf16* base = qkv + (size_t)(b * 2048 + t0 + r) * 3072 + h * 64 + c;
  bf16x8 q0 = *(const bf16x8*)(base);
  bf16x8 q1 = *(const bf16x8*)(base + 8);
  bf16x8 k0 = *(const bf16x8*)(base + 1024);
  bf16x8 k1 = *(const bf16x8*)(base + 1032);
  bf16x8 v0 = *(const bf16x8*)(base + 2048);
  bf16x8 v1 = *(const bf16x8*)(base + 2056);

  const size_t orow = ((size_t)bh * 2048 + t0 + r) * 64 + c;
  *(bf16x8*)(Qb + orow) = q0;
  *(bf16x8*)(Qb + orow + 8) = q1;
  *(bf16x8*)(Kb + orow) = k0;
  *(bf16x8*)(Kb + orow + 8) = k1;

  float* pk = pres + (((size_t)(b * 16 + h)) * 2048 + t0 + r) * 64 + c;
  float* pv = pk + (size_t)2 * 16 * 2048 * 64;
#pragma unroll
  for (int i = 0; i < 4; ++i) {
    float4 fk = {(float)k0[i * 4 + 0], (float)k0[i * 4 + 1],
                 (float)k0[i * 4 + 2], (float)k0[i * 4 + 3]};
    float4 fv = {(float)v0[i * 4 + 0], (float)v0[i * 4 + 1],
                 (float)v0[i * 4 + 2], (float)v0[i * 4 + 3]};
    if (i >= 2) {
      fk = {(float)k1[i * 4 - 8], (float)k1[i * 4 - 7], (float)k1[i * 4 - 6],
            (float)k1[i * 4 - 5]};
      fv = {(float)v1[i * 4 - 8], (float)v1[i * 4 - 7], (float)v1[i * 4 - 6],
            (float)v1[i * 4 - 5]};
    }
    ((float4*)pk)[i] = fk;
    ((float4*)pv)[i] = fv;
  }

  *(bf16x8*)(Vs + r * 72 + c) = v0;
  *(bf16x8*)(Vs + r * 72 + c + 8) = v1;
  __syncthreads();
  // transpose out: thread -> row d, 16 t's
  const int d = tid >> 2, tc = (tid & 3) * 16;
  bf16x8 o0, o1;
#pragma unroll
  for (int i = 0; i < 8; ++i) {
    o0[i] = Vs[(tc + i) * 72 + d];
    o1[i] = Vs[(tc + 8 + i) * 72 + d];
  }
  __bf16* vo = Vtb + ((size_t)bh * 64 + d) * 2048 + t0 + tc;
  *(bf16x8*)(vo) = o0;
  *(bf16x8*)(vo + 8) = o1;
}

// ---------------------------------------------------------------------------
// Flash attention, S^T layout: S^T = K·Q^T via mfma(Kfrag, Qfrag) so q sits on
// l15 -> lane-local online softmax (2 shuffles/reduce), O^T = V^T·P^T.
// Block: paired q-tiles (qt, 31-qt) of 64 rows (4 waves x 16 q), K-tiles of 64.
// Entropy per q: H = m + ln(l) - r/l, r = sum e*s (online-rescaled).
// ---------------------------------------------------------------------------
__global__ __launch_bounds__(256) void attn_kernel(
    const __bf16* __restrict__ Qb, const __bf16* __restrict__ Kb,
    const __bf16* __restrict__ Vtb, __bf16* __restrict__ attn_out,
    float* __restrict__ ent_acc) {
  const int qp = blockIdx.x;  // pair index 0..15
  const int bh = blockIdx.y;  // 0..31
  const int b = bh >> 4, h = bh & 15;
  const int tid = threadIdx.x, w = tid >> 6, lane = tid & 63;
  const int l15 = lane & 15, quad = lane >> 4;

  __shared__ __bf16 Ks[64 * 72];  // [key][d] pad->stride 72 (bank-safe)
  __shared__ __bf16 Vt[64 * 72];  // [d][key]
  __shared__ __bf16 Ps[64 * 72];  // [q][key]
  __shared__ float entred[4];

  const __bf16* qbase = Qb + (size_t)bh * 2048 * 64;
  const __bf16* kbase = Kb + (size_t)bh * 2048 * 64;
  const __bf16* vbase = Vtb + (size_t)bh * 64 * 2048;

  const int sr = tid >> 2, sc = (tid & 3) * 16;  // staging row/col

  float hacc = 0.f;

#pragma unroll 1
  for (int ph = 0; ph < 2; ++ph) {
    const int qt = ph ? (31 - qp) : qp;
    const int q0 = qt * 64;
    const int qrow = q0 + w * 16 + l15;  // this lane's query row
    bf16x8 qf[2];
#pragma unroll
    for (int s = 0; s < 2; ++s)
      qf[s] = *(const bf16x8*)(qbase + (size_t)qrow * 64 + s * 32 + quad * 8);

    f32x4 O[4] = {};
    float m_s = -1e30f, l_s = 0.f, r_s = 0.f;

    for (int kt = 0; kt <= qt; ++kt) {
      const int kk0 = kt * 64;
      __syncthreads();
      {
        bf16x8 k0 = *(const bf16x8*)(kbase + (size_t)(kk0 + sr) * 64 + sc);
        bf16x8 k1 = *(const bf16x8*)(kbase + (size_t)(kk0 + sr) * 64 + sc + 8);
        bf16x8 v0 = *(const bf16x8*)(vbase + (size_t)sr * 2048 + kk0 + sc);
        bf16x8 v1 = *(const bf16x8*)(vbase + (size_t)sr * 2048 + kk0 + sc + 8);
        *(bf16x8*)(Ks + sr * 72 + sc) = k0;
        *(bf16x8*)(Ks + sr * 72 + sc + 8) = k1;
        *(bf16x8*)(Vt + sr * 72 + sc) = v0;
        *(bf16x8*)(Vt + sr * 72 + sc + 8) = v1;
      }
      __syncthreads();

      // S^T: rows=key (reg dim), cols=q (l15)
      f32x4 sacc[4] = {};
#pragma unroll
      for (int s = 0; s < 2; ++s)
#pragma unroll
        for (int jt = 0; jt < 4; ++jt) {
          bf16x8 kf =
              *(const bf16x8*)(Ks + (jt * 16 + l15) * 72 + s * 32 + quad * 8);
          sacc[jt] =
              __builtin_amdgcn_mfma_f32_16x16x32_bf16(kf, qf[s], sacc[jt], 0, 0, 0);
        }

      // mask + lane-local online softmax (lane's keys: kk0+jt*16+quad*4+r)
      float sv[4][4], ev[4][4];
#pragma unroll
      for (int jt = 0; jt < 4; ++jt)
#pragma unroll
        for (int r = 0; r < 4; ++r) {
          float xv = sacc[jt][r] * 0.125f;
          if (kk0 + jt * 16 + quad * 4 + r > qrow) xv = -1e30f;
          sv[jt][r] = xv;
        }
      float mx = sv[0][0];
#pragma unroll
      for (int jt = 0; jt < 4; ++jt)
#pragma unroll
        for (int r = 0; r < 4; ++r) mx = fmaxf(mx, sv[jt][r]);
      mx = fmaxf(mx, __shfl_xor(mx, 16, 64));
      mx = fmaxf(mx, __shfl_xor(mx, 32, 64));
      const float mn = fmaxf(m_s, mx);
      const float al = __expf(m_s - mn);
      m_s = mn;
      float ls = 0.f, rs2 = 0.f;
#pragma unroll
      for (int jt = 0; jt < 4; ++jt)
#pragma unroll
        for (int r = 0; r < 4; ++r) {
          const float e = __expf(sv[jt][r] - mn);
          ev[jt][r] = e;
          ls += e;
          rs2 = fmaf(e, sv[jt][r], rs2);
        }
      ls += __shfl_xor(ls, 16, 64);
      rs2 += __shfl_xor(rs2, 16, 64);
      ls += __shfl_xor(ls, 32, 64);
      rs2 += __shfl_xor(rs2, 32, 64);
      l_s = l_s * al + ls;
      r_s = r_s * al + rs2;
#pragma unroll
      for (int jt = 0; jt < 4; ++jt)
#pragma unroll
        for (int r = 0; r < 4; ++r) O[jt][r] *= al;

      // P^T (key on reg dim) -> Ps[q][key]; lane writes 4 consecutive keys
      __bf16* prow = Ps + (w * 16 + l15) * 72;
#pragma unroll
      for (int jt = 0; jt < 4; ++jt) {
        bf16x4 pk = {(__bf16)ev[jt][0], (__bf16)ev[jt][1], (__bf16)ev[jt][2],
                     (__bf16)ev[jt][3]};
        *(bf16x4*)(prow + jt * 16 + quad * 4) = pk;
      }
      asm volatile("s_waitcnt lgkmcnt(0)" ::: "memory");
      // O^T += V^T · P^T : A=V^T[d][key], B=P[q][key]; C rows=d, cols=q
#pragma unroll
      for (int s = 0; s < 2; ++s) {
        bf16x8 pf = *(const bf16x8*)(prow + s * 32 + quad * 8);
#pragma unroll
        for (int jt = 0; jt < 4; ++jt) {
          bf16x8 vf =
              *(const bf16x8*)(Vt + (jt * 16 + l15) * 72 + s * 32 + quad * 8);
          O[jt] = __builtin_amdgcn_mfma_f32_16x16x32_bf16(vf, pf, O[jt], 0, 0, 0);
        }
      }
    }

    // finalize this phase: lane owns q=qrow; O[jt][r] is d = jt*16+quad*4+r
    const float inv = 1.0f / l_s;
    __bf16* obase = attn_out + (size_t)(b * 2048 + qrow) * 1024 + h * 64;
#pragma unroll
    for (int jt = 0; jt < 4; ++jt) {
      bf16x4 ov = {(__bf16)(O[jt][0] * inv), (__bf16)(O[jt][1] * inv),
                   (__bf16)(O[jt][2] * inv), (__bf16)(O[jt][3] * inv)};
      *(bf16x4*)(obase + jt * 16 + quad * 4) = ov;
    }
    hacc += m_s + __logf(l_s) - r_s * inv;  // replicated x4 across quads
  }

  // entropy reduce: 64-lane sum (4x replication corrected below)
#pragma unroll
  for (int m = 1; m < 64; m <<= 1) hacc += __shfl_xor(hacc, m, 64);
  if (lane == 0) entred[w] = hacc;
  __syncthreads();
  if (tid == 0)
    atomicAdd(ent_acc, (entred[0] + entred[1] + entred[2] + entred[3]) *
                           (1.0f / (4.0f * 65536.0f)));
}

__global__ void ent_final(const float* __restrict__ e, float* __restrict__ o) {
  if (threadIdx.x == 0) o[0] = e[0];
}

// ---------------------------------------------------------------------------
extern "C" void kernel_launch(void* const* d_in, const int* in_sizes, int n_in,
                              void* d_out, int out_size, void* d_ws,
                              size_t ws_size, hipStream_t stream) {
  const float* x      = (const float*)d_in[0];
  const float* ln1_w  = (const float*)d_in[1];
  const float* ln1_b  = (const float*)d_in[2];
  const float* w_attn = (const float*)d_in[3];
  const float* b_attn = (const float*)d_in[4];
  const float* w_proj = (const float*)d_in[5];
  const float* b_proj = (const float*)d_in[6];
  const float* ln2_w  = (const float*)d_in[7];
  const float* ln2_b  = (const float*)d_in[8];
  const float* w_fc   = (const float*)d_in[9];
  const float* b_fc   = (const float*)d_in[10];
  const float* w_mlp  = (const float*)d_in[11];
  const float* b_mlp  = (const float*)d_in[12];

  char* ws = (char*)d_ws;
  constexpr size_t MB = 1024ull * 1024ull;
  // lifetimes: qkv [0,24) dead after prep; act [0,32) lives fc..mlp.
  // hb [40,48) lives ln1->qkv-gemm, then reused as Vtb (prep->attn), then ln2.
  // Qb [48,56), Kb [56,64) live prep->attn; x2 [48,64) written at proj (after).
  __bf16* qkv    = (__bf16*)(ws + 0);
  __bf16* act    = (__bf16*)(ws + 0);
  __bf16* wbattn = (__bf16*)(ws + 24 * MB);
  __bf16* wbproj = (__bf16*)(ws + 30 * MB);
  __bf16* attnb  = (__bf16*)(ws + 32 * MB);
  __bf16* hb     = (__bf16*)(ws + 40 * MB);
  __bf16* Vtb    = (__bf16*)(ws + 40 * MB);
  __bf16* Qb     = (__bf16*)(ws + 48 * MB);
  __bf16* Kb     = (__bf16*)(ws + 56 * MB);
  float*  x2     = (float*)(ws + 48 * MB);
  __bf16* wbfc   = (__bf16*)(ws + 64 * MB);
  __bf16* wbmlp  = (__bf16*)(ws + 72 * MB);
  float*  entw   = (float*)(ws + 80 * MB);

  float* xout   = (float*)d_out;
  float* entout = xout + 4194304;
  float* pres   = xout + 4194305;

  hipMemsetAsync(entw, 0, sizeof(float), stream);
  cast_w<<<dim3(4096, 4), 256, 0, stream>>>(
      w_attn, w_proj, w_fc, w_mlp, wbattn, wbproj, wbfc, wbmlp,
      3 * 1024 * 1024, 1024 * 1024, 4 * 1024 * 1024, 4 * 1024 * 1024);
  ln_kernel<<<4096, 256, 0, stream>>>(x, ln1_w, ln1_b, hb);
  gemm_bt<0, 128><<<dim3(24, 32), 256, 0, stream>>>(
      hb, wbattn, b_attn, nullptr, nullptr, qkv, 4096, 3072, 1024);
  prep_kernel<<<dim3(32, 32), 256, 0, stream>>>(qkv, Qb, Kb, Vtb, pres);
  attn_kernel<<<dim3(16, 32), 256, 0, stream>>>(Qb, Kb, Vtb, attnb, entw);
  gemm_bt<1, 64><<<dim3(16, 32), 256, 0, stream>>>(
      attnb, wbproj, b_proj, x, x2, nullptr, 4096, 1024, 1024);
  ln_kernel<<<4096, 256, 0, stream>>>(x2, ln2_w, ln2_b, hb);
  gemm_bt<2, 128><<<dim3(32, 32), 256, 0, stream>>>(
      hb, wbfc, b_fc, nullptr, nullptr, act, 4096, 4096, 1024);
  gemm_bt<1, 64><<<dim3(16, 32), 256, 0, stream>>>(
      act, wbmlp, b_mlp, x2, xout, nullptr, 4096, 1024, 4096);
  ent_final<<<1, 64, 0, stream>>>(entw, entout);
}

// Round 3
// 427.360 us; speedup vs baseline: 1.3564x; 1.0056x over previous
//
#include <hip/hip_runtime.h>
#include <hip/hip_bf16.h>
#include <stdint.h>

// ---------------------------------------------------------------------------
// Transformer block fwd on gfx950. bf16 MFMA GEMMs + S^T-layout flash attn.
// B=2 T=2048 C=1024 H=16 HD=64.
// ---------------------------------------------------------------------------

typedef __bf16 bf16x8 __attribute__((ext_vector_type(8)));
typedef __bf16 bf16x4 __attribute__((ext_vector_type(4)));
typedef float  f32x4  __attribute__((ext_vector_type(4)));

#define GLDS16(g, l)                                                          \
  __builtin_amdgcn_global_load_lds(                                           \
      (__attribute__((address_space(1))) void*)(g),                           \
      (__attribute__((address_space(3))) void*)(l), 16, 0, 0)

// gelu(x) = 0.5x(1+tanh(u)) = x * sigmoid(2u); one v_exp + one v_rcp.
__device__ __forceinline__ float gelu_f(float x) {
  float u2 = 1.5957691216057308f * (x + 0.044715f * x * x * x);
  return x * __builtin_amdgcn_rcpf(1.0f + __expf(-u2));
}

// ---------------------------------------------------------------------------
// cast 4 fp32 weight matrices to bf16 (blockIdx.y selects array)
// ---------------------------------------------------------------------------
__global__ __launch_bounds__(256) void cast_w(
    const float* s0, const float* s1, const float* s2, const float* s3,
    __bf16* d0, __bf16* d1, __bf16* d2, __bf16* d3,
    int n0, int n1, int n2, int n3) {
  int a = blockIdx.y;
  const float* s = (a == 0) ? s0 : (a == 1) ? s1 : (a == 2) ? s2 : s3;
  __bf16* d      = (a == 0) ? d0 : (a == 1) ? d1 : (a == 2) ? d2 : d3;
  int n          = (a == 0) ? n0 : (a == 1) ? n1 : (a == 2) ? n2 : n3;
  int i = (blockIdx.x * 256 + threadIdx.x) * 4;
  if (i < n) {
    float4 v = *(const float4*)(s + i);
    bf16x4 o = {(__bf16)v.x, (__bf16)v.y, (__bf16)v.z, (__bf16)v.w};
    *(bf16x4*)(d + i) = o;
  }
}

// ---------------------------------------------------------------------------
// LayerNorm over C=1024, one block (256 thr) per row; bf16 output
// ---------------------------------------------------------------------------
__global__ __launch_bounds__(256) void ln_kernel(
    const float* __restrict__ x, const float* __restrict__ gw,
    const float* __restrict__ gb, __bf16* __restrict__ out) {
  const int row = blockIdx.x, tid = threadIdx.x;
  const float4 v = ((const float4*)(x + (size_t)row * 1024))[tid];
  float s = v.x + v.y + v.z + v.w;
  float sq = v.x * v.x + v.y * v.y + v.z * v.z + v.w * v.w;
#pragma unroll
  for (int m = 1; m < 64; m <<= 1) {
    s += __shfl_xor(s, m, 64);
    sq += __shfl_xor(sq, m, 64);
  }
  __shared__ float red[8];
  if ((tid & 63) == 0) { red[tid >> 6] = s; red[4 + (tid >> 6)] = sq; }
  __syncthreads();
  s = red[0] + red[1] + red[2] + red[3];
  sq = red[4] + red[5] + red[6] + red[7];
  const float mu = s * (1.0f / 1024.0f);
  const float var = sq * (1.0f / 1024.0f) - mu * mu;
  const float rs = rsqrtf(var + 1e-5f);
  const float4 wv = ((const float4*)gw)[tid];
  const float4 bv = ((const float4*)gb)[tid];
  bf16x4 o;
  o[0] = (__bf16)((v.x - mu) * rs * wv.x + bv.x);
  o[1] = (__bf16)((v.y - mu) * rs * wv.y + bv.y);
  o[2] = (__bf16)((v.z - mu) * rs * wv.z + bv.z);
  o[3] = (__bf16)((v.w - mu) * rs * wv.w + bv.w);
  *(bf16x4*)(out + (size_t)row * 1024 + tid * 4) = o;
}

// ---------------------------------------------------------------------------
// GEMM: C[M,N] = A[M,K] * Bw[N,K]^T (+bias, epilogue). m97 structure:
// 128xBN tile, BK=32, global_load_lds width 16, 4 waves MFMA 16x16x32.
// Operand-SWAPPED mfma(B,A): D rows = n (quad*4+r), cols = m (l15) so each
// lane holds 4 consecutive n -> vectorized 8B/16B epilogue stores.
// EPI: 0 = bias -> bf16; 1 = bias + fp32 resid -> fp32; 2 = bias+gelu -> bf16
// ---------------------------------------------------------------------------
template <int EPI, int BN>
__global__ __launch_bounds__(256) void gemm_bt(
    const __bf16* __restrict__ A, const __bf16* __restrict__ Bw,
    const float* __restrict__ bias, const float* __restrict__ resid,
    float* __restrict__ outF, __bf16* __restrict__ outH, int M, int N, int K) {
  __shared__ __bf16 As[128 * 32];
  __shared__ __bf16 Bs[BN * 32];
  constexpr int JN = BN / 32;  // n-subtiles per wave
  const int tid = threadIdx.x;
  const int w = tid >> 6, lane = tid & 63, l15 = lane & 15, quad = lane >> 4;
  const int wm = (w >> 1) * 64, wn = (w & 1) * (BN / 2);
  const int m0 = blockIdx.y * 128, n0 = blockIdx.x * BN;
  const int arow = tid >> 2, acol = (tid & 3) * 8;

  f32x4 acc[4][JN] = {};

  const __bf16* ga = A + (size_t)(m0 + arow) * K + acol;
  const __bf16* gb = Bw + (size_t)(n0 + arow) * K + acol;
  for (int k0 = 0; k0 < K; k0 += 32) {
    __syncthreads();
    GLDS16(ga + k0, (char*)As + tid * 16);
    GLDS16(ga + k0 + (size_t)64 * K, (char*)As + 4096 + tid * 16);
    GLDS16(gb + k0, (char*)Bs + tid * 16);
    if (BN == 128)
      GLDS16(gb + k0 + (size_t)64 * K, (char*)Bs + 4096 + tid * 16);
    __syncthreads();
    bf16x8 af[4], bfr[JN];
#pragma unroll
    for (int i = 0; i < 4; ++i)
      af[i] = *(const bf16x8*)(As + (wm + i * 16 + l15) * 32 + quad * 8);
#pragma unroll
    for (int j = 0; j < JN; ++j)
      bfr[j] = *(const bf16x8*)(Bs + (wn + j * 16 + l15) * 32 + quad * 8);
#pragma unroll
    for (int i = 0; i < 4; ++i)
#pragma unroll
      for (int j = 0; j < JN; ++j)
        acc[i][j] = __builtin_amdgcn_mfma_f32_16x16x32_bf16(bfr[j], af[i],
                                                            acc[i][j], 0, 0, 0);
  }
  // epilogue (swapped D): n = n0+wn+j*16+quad*4+r, m = m0+wm+i*16+l15
#pragma unroll
  for (int j = 0; j < JN; ++j) {
    const int nb = n0 + wn + j * 16 + quad * 4;
    const float4 bv = *(const float4*)(bias + nb);
#pragma unroll
    for (int i = 0; i < 4; ++i) {
      const int m = m0 + wm + i * 16 + l15;
      const size_t idx = (size_t)m * N + nb;
      const float v0 = acc[i][j][0] + bv.x;
      const float v1 = acc[i][j][1] + bv.y;
      const float v2 = acc[i][j][2] + bv.z;
      const float v3 = acc[i][j][3] + bv.w;
      if (EPI == 0) {
        bf16x4 o = {(__bf16)v0, (__bf16)v1, (__bf16)v2, (__bf16)v3};
        *(bf16x4*)(outH + idx) = o;
      } else if (EPI == 1) {
        const float4 rv = *(const float4*)(resid + idx);
        float4 o = {v0 + rv.x, v1 + rv.y, v2 + rv.z, v3 + rv.w};
        *(float4*)(outF + idx) = o;
      } else {
        bf16x4 o = {(__bf16)gelu_f(v0), (__bf16)gelu_f(v1), (__bf16)gelu_f(v2),
                    (__bf16)gelu_f(v3)};
        *(bf16x4*)(outH + idx) = o;
      }
    }
  }
}

// ---------------------------------------------------------------------------
// prep: from qkv (B,T,3C) bf16 produce
//   Qb,Kb : (B,H,T,64) bf16;  Vtb : (B,H,64,T) bf16 (pre-transposed V)
//   pres  : (2,B,H,T,64) fp32 (the `present` output)
// ---------------------------------------------------------------------------
__global__ __launch_bounds__(256) void prep_kernel(
    const __bf16* __restrict__ qkv, __bf16* __restrict__ Qb,
    __bf16* __restrict__ Kb, __bf16* __restrict__ Vtb,
    float* __restrict__ pres) {
  const int tt = blockIdx.x, bh = blockIdx.y;
  const int b = bh >> 4, h = bh & 15;
  const int t0 = tt * 64, tid = threadIdx.x;
  const int r = tid >> 2, c = (tid & 3) * 16;
  __shared__ __bf16 Vs[64 * 72];

  const __bf16* base = qkv + (size_t)(b * 2048 + t0 + r) * 3072 + h * 64 + c;
  bf16x8 q0 = *(const bf16x8*)(base);
  bf16x8 q1 = *(const bf16x8*)(base + 8);
  bf16x8 k0 = *(const bf16x8*)(base + 1024);
  bf16x8 k1 = *(const bf16x8*)(base + 1032);
  bf16x8 v0 = *(const bf16x8*)(base + 2048);
  bf16x8 v1 = *(const bf16x8*)(base + 2056);

  const size_t orow = ((size_t)bh * 2048 + t0 + r) * 64 + c;
  *(bf16x8*)(Qb + orow) = q0;
  *(bf16x8*)(Qb + orow + 8) = q1;
  *(bf16x8*)(Kb + orow) = k0;
  *(bf16x8*)(Kb + orow + 8) = k1;

  float* pk = pres + (((size_t)(b * 16 + h)) * 2048 + t0 + r) * 64 + c;
  float* pv = pk + (size_t)2 * 16 * 2048 * 64;
#pragma unroll
  for (int i = 0; i < 4; ++i) {
    float4 fk = {(float)k0[i * 4 + 0], (float)k0[i * 4 + 1],
                 (float)k0[i * 4 + 2], (float)k0[i * 4 + 3]};
    float4 fv = {(float)v0[i * 4 + 0], (float)v0[i * 4 + 1],
                 (float)v0[i * 4 + 2], (float)v0[i * 4 + 3]};
    if (i >= 2) {
      fk = {(float)k1[i * 4 - 8], (float)k1[i * 4 - 7], (float)k1[i * 4 - 6],
            (float)k1[i * 4 - 5]};
      fv = {(float)v1[i * 4 - 8], (float)v1[i * 4 - 7], (float)v1[i * 4 - 6],
            (float)v1[i * 4 - 5]};
    }
    ((float4*)pk)[i] = fk;
    ((float4*)pv)[i] = fv;
  }

  *(bf16x8*)(Vs + r * 72 + c) = v0;
  *(bf16x8*)(Vs + r * 72 + c + 8) = v1;
  __syncthreads();
  const int d = tid >> 2, tc = (tid & 3) * 16;
  bf16x8 o0, o1;
#pragma unroll
  for (int i = 0; i < 8; ++i) {
    o0[i] = Vs[(tc + i) * 72 + d];
    o1[i] = Vs[(tc + 8 + i) * 72 + d];
  }
  __bf16* vo = Vtb + ((size_t)bh * 64 + d) * 2048 + t0 + tc;
  *(bf16x8*)(vo) = o0;
  *(bf16x8*)(vo + 8) = o1;
}

// ---------------------------------------------------------------------------
// Flash attention, S^T layout (q on l15 -> lane-local online softmax).
// Block: paired q-tiles (qt, 31-qt); K-tiles of 64; entropy H = m+ln l - r/l.
// ---------------------------------------------------------------------------
__global__ __launch_bounds__(256) void attn_kernel(
    const __bf16* __restrict__ Qb, const __bf16* __restrict__ Kb,
    const __bf16* __restrict__ Vtb, __bf16* __restrict__ attn_out,
    float* __restrict__ ent_acc) {
  const int qp = blockIdx.x;  // pair index 0..15
  const int bh = blockIdx.y;  // 0..31
  const int b = bh >> 4, h = bh & 15;
  const int tid = threadIdx.x, w = tid >> 6, lane = tid & 63;
  const int l15 = lane & 15, quad = lane >> 4;

  __shared__ __bf16 Ks[64 * 72];
  __shared__ __bf16 Vt[64 * 72];
  __shared__ __bf16 Ps[64 * 72];
  __shared__ float entred[4];

  const __bf16* qbase = Qb + (size_t)bh * 2048 * 64;
  const __bf16* kbase = Kb + (size_t)bh * 2048 * 64;
  const __bf16* vbase = Vtb + (size_t)bh * 64 * 2048;

  const int sr = tid >> 2, sc = (tid & 3) * 16;

  float hacc = 0.f;

#pragma unroll 1
  for (int ph = 0; ph < 2; ++ph) {
    const int qt = ph ? (31 - qp) : qp;
    const int q0 = qt * 64;
    const int qrow = q0 + w * 16 + l15;
    bf16x8 qf[2];
#pragma unroll
    for (int s = 0; s < 2; ++s)
      qf[s] = *(const bf16x8*)(qbase + (size_t)qrow * 64 + s * 32 + quad * 8);

    f32x4 O[4] = {};
    float m_s = -1e30f, l_s = 0.f, r_s = 0.f;

    for (int kt = 0; kt <= qt; ++kt) {
      const int kk0 = kt * 64;
      __syncthreads();
      {
        bf16x8 k0 = *(const bf16x8*)(kbase + (size_t)(kk0 + sr) * 64 + sc);
        bf16x8 k1 = *(const bf16x8*)(kbase + (size_t)(kk0 + sr) * 64 + sc + 8);
        bf16x8 v0 = *(const bf16x8*)(vbase + (size_t)sr * 2048 + kk0 + sc);
        bf16x8 v1 = *(const bf16x8*)(vbase + (size_t)sr * 2048 + kk0 + sc + 8);
        *(bf16x8*)(Ks + sr * 72 + sc) = k0;
        *(bf16x8*)(Ks + sr * 72 + sc + 8) = k1;
        *(bf16x8*)(Vt + sr * 72 + sc) = v0;
        *(bf16x8*)(Vt + sr * 72 + sc + 8) = v1;
      }
      __syncthreads();

      f32x4 sacc[4] = {};
#pragma unroll
      for (int s = 0; s < 2; ++s)
#pragma unroll
        for (int jt = 0; jt < 4; ++jt) {
          bf16x8 kf =
              *(const bf16x8*)(Ks + (jt * 16 + l15) * 72 + s * 32 + quad * 8);
          sacc[jt] =
              __builtin_amdgcn_mfma_f32_16x16x32_bf16(kf, qf[s], sacc[jt], 0, 0, 0);
        }

      float sv[4][4], ev[4][4];
#pragma unroll
      for (int jt = 0; jt < 4; ++jt)
#pragma unroll
        for (int r = 0; r < 4; ++r) {
          float xv = sacc[jt][r] * 0.125f;
          if (kk0 + jt * 16 + quad * 4 + r > qrow) xv = -1e30f;
          sv[jt][r] = xv;
        }
      float mx = sv[0][0];
#pragma unroll
      for (int jt = 0; jt < 4; ++jt)
#pragma unroll
        for (int r = 0; r < 4; ++r) mx = fmaxf(mx, sv[jt][r]);
      mx = fmaxf(mx, __shfl_xor(mx, 16, 64));
      mx = fmaxf(mx, __shfl_xor(mx, 32, 64));
      const float mn = fmaxf(m_s, mx);
      const float al = __expf(m_s - mn);
      m_s = mn;
      float ls = 0.f, rs2 = 0.f;
#pragma unroll
      for (int jt = 0; jt < 4; ++jt)
#pragma unroll
        for (int r = 0; r < 4; ++r) {
          const float e = __expf(sv[jt][r] - mn);
          ev[jt][r] = e;
          ls += e;
          rs2 = fmaf(e, sv[jt][r], rs2);
        }
      ls += __shfl_xor(ls, 16, 64);
      rs2 += __shfl_xor(rs2, 16, 64);
      ls += __shfl_xor(ls, 32, 64);
      rs2 += __shfl_xor(rs2, 32, 64);
      l_s = l_s * al + ls;
      r_s = r_s * al + rs2;
#pragma unroll
      for (int jt = 0; jt < 4; ++jt)
#pragma unroll
        for (int r = 0; r < 4; ++r) O[jt][r] *= al;

      __bf16* prow = Ps + (w * 16 + l15) * 72;
#pragma unroll
      for (int jt = 0; jt < 4; ++jt) {
        bf16x4 pk = {(__bf16)ev[jt][0], (__bf16)ev[jt][1], (__bf16)ev[jt][2],
                     (__bf16)ev[jt][3]};
        *(bf16x4*)(prow + jt * 16 + quad * 4) = pk;
      }
      asm volatile("s_waitcnt lgkmcnt(0)" ::: "memory");
#pragma unroll
      for (int s = 0; s < 2; ++s) {
        bf16x8 pf = *(const bf16x8*)(prow + s * 32 + quad * 8);
#pragma unroll
        for (int jt = 0; jt < 4; ++jt) {
          bf16x8 vf =
              *(const bf16x8*)(Vt + (jt * 16 + l15) * 72 + s * 32 + quad * 8);
          O[jt] = __builtin_amdgcn_mfma_f32_16x16x32_bf16(vf, pf, O[jt], 0, 0, 0);
        }
      }
    }

    const float inv = 1.0f / l_s;
    __bf16* obase = attn_out + (size_t)(b * 2048 + qrow) * 1024 + h * 64;
#pragma unroll
    for (int jt = 0; jt < 4; ++jt) {
      bf16x4 ov = {(__bf16)(O[jt][0] * inv), (__bf16)(O[jt][1] * inv),
                   (__bf16)(O[jt][2] * inv), (__bf16)(O[jt][3] * inv)};
      *(bf16x4*)(obase + jt * 16 + quad * 4) = ov;
    }
    hacc += m_s + __logf(l_s) - r_s * inv;  // replicated x4 across quads
  }

#pragma unroll
  for (int m = 1; m < 64; m <<= 1) hacc += __shfl_xor(hacc, m, 64);
  if (lane == 0) entred[w] = hacc;
  __syncthreads();
  if (tid == 0)
    atomicAdd(ent_acc, (entred[0] + entred[1] + entred[2] + entred[3]) *
                           (1.0f / (4.0f * 65536.0f)));
}

__global__ void ent_final(const float* __restrict__ e, float* __restrict__ o) {
  if (threadIdx.x == 0) o[0] = e[0];
}

// ---------------------------------------------------------------------------
extern "C" void kernel_launch(void* const* d_in, const int* in_sizes, int n_in,
                              void* d_out, int out_size, void* d_ws,
                              size_t ws_size, hipStream_t stream) {
  const float* x      = (const float*)d_in[0];
  const float* ln1_w  = (const float*)d_in[1];
  const float* ln1_b  = (const float*)d_in[2];
  const float* w_attn = (const float*)d_in[3];
  const float* b_attn = (const float*)d_in[4];
  const float* w_proj = (const float*)d_in[5];
  const float* b_proj = (const float*)d_in[6];
  const float* ln2_w  = (const float*)d_in[7];
  const float* ln2_b  = (const float*)d_in[8];
  const float* w_fc   = (const float*)d_in[9];
  const float* b_fc   = (const float*)d_in[10];
  const float* w_mlp  = (const float*)d_in[11];
  const float* b_mlp  = (const float*)d_in[12];

  char* ws = (char*)d_ws;
  constexpr size_t MB = 1024ull * 1024ull;
  __bf16* qkv    = (__bf16*)(ws + 0);
  __bf16* act    = (__bf16*)(ws + 0);
  __bf16* wbattn = (__bf16*)(ws + 24 * MB);
  __bf16* wbproj = (__bf16*)(ws + 30 * MB);
  __bf16* attnb  = (__bf16*)(ws + 32 * MB);
  __bf16* hb     = (__bf16*)(ws + 40 * MB);
  __bf16* Vtb    = (__bf16*)(ws + 40 * MB);
  __bf16* Qb     = (__bf16*)(ws + 48 * MB);
  __bf16* Kb     = (__bf16*)(ws + 56 * MB);
  float*  x2     = (float*)(ws + 48 * MB);
  __bf16* wbfc   = (__bf16*)(ws + 64 * MB);
  __bf16* wbmlp  = (__bf16*)(ws + 72 * MB);
  float*  entw   = (float*)(ws + 80 * MB);

  float* xout   = (float*)d_out;
  float* entout = xout + 4194304;
  float* pres   = xout + 4194305;

  hipMemsetAsync(entw, 0, sizeof(float), stream);
  cast_w<<<dim3(4096, 4), 256, 0, stream>>>(
      w_attn, w_proj, w_fc, w_mlp, wbattn, wbproj, wbfc, wbmlp,
      3 * 1024 * 1024, 1024 * 1024, 4 * 1024 * 1024, 4 * 1024 * 1024);
  ln_kernel<<<4096, 256, 0, stream>>>(x, ln1_w, ln1_b, hb);
  gemm_bt<0, 128><<<dim3(24, 32), 256, 0, stream>>>(
      hb, wbattn, b_attn, nullptr, nullptr, qkv, 4096, 3072, 1024);
  prep_kernel<<<dim3(32, 32), 256, 0, stream>>>(qkv, Qb, Kb, Vtb, pres);
  attn_kernel<<<dim3(16, 32), 256, 0, stream>>>(Qb, Kb, Vtb, attnb, entw);
  gemm_bt<1, 64><<<dim3(16, 32), 256, 0, stream>>>(
      attnb, wbproj, b_proj, x, x2, nullptr, 4096, 1024, 1024);
  ln_kernel<<<4096, 256, 0, stream>>>(x2, ln2_w, ln2_b, hb);
  gemm_bt<2, 128><<<dim3(32, 32), 256, 0, stream>>>(
      hb, wbfc, b_fc, nullptr, nullptr, act, 4096, 4096, 1024);
  gemm_bt<1, 64><<<dim3(16, 32), 256, 0, stream>>>(
      act, wbmlp, b_mlp, x2, xout, nullptr, 4096, 1024, 4096);
  ent_final<<<1, 64, 0, stream>>>(entw, entout);
}

// Round 4
// 383.236 us; speedup vs baseline: 1.5125x; 1.1151x over previous
//
#include <hip/hip_runtime.h>
#include <hip/hip_bf16.h>
#include <stdint.h>

// ---------------------------------------------------------------------------
// Transformer block fwd on gfx950. bf16 MFMA GEMMs + S^T-layout flash attn.
// B=2 T=2048 C=1024 H=16 HD=64.
// ---------------------------------------------------------------------------

typedef __bf16 bf16x8 __attribute__((ext_vector_type(8)));
typedef __bf16 bf16x4 __attribute__((ext_vector_type(4)));
typedef float  f32x4  __attribute__((ext_vector_type(4)));

#define GLDS16(g, l)                                                          \
  __builtin_amdgcn_global_load_lds(                                           \
      (__attribute__((address_space(1))) void*)(g),                           \
      (__attribute__((address_space(3))) void*)(l), 16, 0, 0)

// gelu(x) = 0.5x(1+tanh(u)) = x * sigmoid(2u); one v_exp + one v_rcp.
__device__ __forceinline__ float gelu_f(float x) {
  float u2 = 1.5957691216057308f * (x + 0.044715f * x * x * x);
  return x * __builtin_amdgcn_rcpf(1.0f + __expf(-u2));
}

// ---------------------------------------------------------------------------
// cast 4 fp32 weight matrices to bf16 (blockIdx.y selects array)
// ---------------------------------------------------------------------------
__global__ __launch_bounds__(256) void cast_w(
    const float* s0, const float* s1, const float* s2, const float* s3,
    __bf16* d0, __bf16* d1, __bf16* d2, __bf16* d3,
    int n0, int n1, int n2, int n3) {
  int a = blockIdx.y;
  const float* s = (a == 0) ? s0 : (a == 1) ? s1 : (a == 2) ? s2 : s3;
  __bf16* d      = (a == 0) ? d0 : (a == 1) ? d1 : (a == 2) ? d2 : d3;
  int n          = (a == 0) ? n0 : (a == 1) ? n1 : (a == 2) ? n2 : n3;
  int i = (blockIdx.x * 256 + threadIdx.x) * 4;
  if (i < n) {
    float4 v = *(const float4*)(s + i);
    bf16x4 o = {(__bf16)v.x, (__bf16)v.y, (__bf16)v.z, (__bf16)v.w};
    *(bf16x4*)(d + i) = o;
  }
}

// ---------------------------------------------------------------------------
// LayerNorm over C=1024, one block (256 thr) per row; bf16 output
// ---------------------------------------------------------------------------
__global__ __launch_bounds__(256) void ln_kernel(
    const float* __restrict__ x, const float* __restrict__ gw,
    const float* __restrict__ gb, __bf16* __restrict__ out) {
  const int row = blockIdx.x, tid = threadIdx.x;
  const float4 v = ((const float4*)(x + (size_t)row * 1024))[tid];
  float s = v.x + v.y + v.z + v.w;
  float sq = v.x * v.x + v.y * v.y + v.z * v.z + v.w * v.w;
#pragma unroll
  for (int m = 1; m < 64; m <<= 1) {
    s += __shfl_xor(s, m, 64);
    sq += __shfl_xor(sq, m, 64);
  }
  __shared__ float red[8];
  if ((tid & 63) == 0) { red[tid >> 6] = s; red[4 + (tid >> 6)] = sq; }
  __syncthreads();
  s = red[0] + red[1] + red[2] + red[3];
  sq = red[4] + red[5] + red[6] + red[7];
  const float mu = s * (1.0f / 1024.0f);
  const float var = sq * (1.0f / 1024.0f) - mu * mu;
  const float rs = rsqrtf(var + 1e-5f);
  const float4 wv = ((const float4*)gw)[tid];
  const float4 bv = ((const float4*)gb)[tid];
  bf16x4 o;
  o[0] = (__bf16)((v.x - mu) * rs * wv.x + bv.x);
  o[1] = (__bf16)((v.y - mu) * rs * wv.y + bv.y);
  o[2] = (__bf16)((v.z - mu) * rs * wv.z + bv.z);
  o[3] = (__bf16)((v.w - mu) * rs * wv.w + bv.w);
  *(bf16x4*)(out + (size_t)row * 1024 + tid * 4) = o;
}

// ---------------------------------------------------------------------------
// GEMM: C[M,N] = A[M,K] * Bw[N,K]^T (+bias, epilogue).
// 128xBN tile, BK=64 as TWO k-half LDS stages (same bank-free addressing as
// BK=32, half the barriers). global_load_lds width 16. Operand-swapped
// mfma(B,A): D rows = n, cols = m -> vectorized stores.
// XCD swizzle: blocks sharing an A row-tile land on one XCD (L2 reuse).
// EPI: 0 = bias -> bf16; 1 = bias + fp32 resid -> fp32; 2 = bias+gelu -> bf16
// ---------------------------------------------------------------------------
template <int EPI, int BN, int MINW>
__global__ __launch_bounds__(256, MINW) void gemm_bt(
    const __bf16* __restrict__ A, const __bf16* __restrict__ Bw,
    const float* __restrict__ bias, const float* __restrict__ resid,
    float* __restrict__ outF, __bf16* __restrict__ outH, int M, int N, int K) {
  __shared__ __bf16 As[2][128 * 32];
  __shared__ __bf16 Bs[2][BN * 32];
  constexpr int JN = BN / 32;  // n-subtiles per wave
  const int tid = threadIdx.x;
  const int w = tid >> 6, lane = tid & 63, l15 = lane & 15, quad = lane >> 4;
  const int wm = (w >> 1) * 64, wn = (w & 1) * (BN / 2);
  // XCD-aware swizzle: xcd = j&7 owns y-band [xcd*ny/8, ...), x fastest.
  const int nx = gridDim.x;
  const int j = blockIdx.y * nx + blockIdx.x;
  const int xcd = j & 7, u = j >> 3;
  const int yl = u / nx, xx = u - yl * nx;
  const int yy = xcd * (gridDim.y >> 3) + yl;
  const int m0 = yy * 128, n0 = xx * BN;
  const int arow = tid >> 2, acol = (tid & 3) * 8;

  f32x4 acc[4][JN] = {};

  const __bf16* ga = A + (size_t)(m0 + arow) * K + acol;
  const __bf16* gb = Bw + (size_t)(n0 + arow) * K + acol;
  for (int k0 = 0; k0 < K; k0 += 64) {
    __syncthreads();
#pragma unroll
    for (int h = 0; h < 2; ++h) {
      GLDS16(ga + k0 + h * 32, (char*)As[h] + tid * 16);
      GLDS16(ga + k0 + h * 32 + (size_t)64 * K, (char*)As[h] + 4096 + tid * 16);
      GLDS16(gb + k0 + h * 32, (char*)Bs[h] + tid * 16);
      if (BN == 128)
        GLDS16(gb + k0 + h * 32 + (size_t)64 * K,
               (char*)Bs[h] + 4096 + tid * 16);
    }
    __syncthreads();
#pragma unroll
    for (int h = 0; h < 2; ++h) {
      bf16x8 af[4], bfr[JN];
#pragma unroll
      for (int i = 0; i < 4; ++i)
        af[i] = *(const bf16x8*)(As[h] + (wm + i * 16 + l15) * 32 + quad * 8);
#pragma unroll
      for (int j2 = 0; j2 < JN; ++j2)
        bfr[j2] = *(const bf16x8*)(Bs[h] + (wn + j2 * 16 + l15) * 32 + quad * 8);
#pragma unroll
      for (int i = 0; i < 4; ++i)
#pragma unroll
        for (int j2 = 0; j2 < JN; ++j2)
          acc[i][j2] = __builtin_amdgcn_mfma_f32_16x16x32_bf16(
              bfr[j2], af[i], acc[i][j2], 0, 0, 0);
    }
  }
  // epilogue (swapped D): n = n0+wn+j*16+quad*4+r, m = m0+wm+i*16+l15
#pragma unroll
  for (int j2 = 0; j2 < JN; ++j2) {
    const int nb = n0 + wn + j2 * 16 + quad * 4;
    const float4 bv = *(const float4*)(bias + nb);
#pragma unroll
    for (int i = 0; i < 4; ++i) {
      const int m = m0 + wm + i * 16 + l15;
      const size_t idx = (size_t)m * N + nb;
      const float v0 = acc[i][j2][0] + bv.x;
      const float v1 = acc[i][j2][1] + bv.y;
      const float v2 = acc[i][j2][2] + bv.z;
      const float v3 = acc[i][j2][3] + bv.w;
      if (EPI == 0) {
        bf16x4 o = {(__bf16)v0, (__bf16)v1, (__bf16)v2, (__bf16)v3};
        *(bf16x4*)(outH + idx) = o;
      } else if (EPI == 1) {
        const float4 rv = *(const float4*)(resid + idx);
        float4 o = {v0 + rv.x, v1 + rv.y, v2 + rv.z, v3 + rv.w};
        *(float4*)(outF + idx) = o;
      } else {
        bf16x4 o = {(__bf16)gelu_f(v0), (__bf16)gelu_f(v1), (__bf16)gelu_f(v2),
                    (__bf16)gelu_f(v3)};
        *(bf16x4*)(outH + idx) = o;
      }
    }
  }
}

// ---------------------------------------------------------------------------
// prep: from qkv (B,T,3C) bf16 produce
//   Qb,Kb : (B,H,T,64) bf16;  Vtb : (B,H,64,T) bf16 (pre-transposed V)
//   pres  : (2,B,H,T,64) fp32 (the `present` output)
// ---------------------------------------------------------------------------
__global__ __launch_bounds__(256) void prep_kernel(
    const __bf16* __restrict__ qkv, __bf16* __restrict__ Qb,
    __bf16* __restrict__ Kb, __bf16* __restrict__ Vtb,
    float* __restrict__ pres) {
  const int tt = blockIdx.x, bh = blockIdx.y;
  const int b = bh >> 4, h = bh & 15;
  const int t0 = tt * 64, tid = threadIdx.x;
  const int r = tid >> 2, c = (tid & 3) * 16;
  __shared__ __bf16 Vs[64 * 72];

  const __bf16* base = qkv + (size_t)(b * 2048 + t0 + r) * 3072 + h * 64 + c;
  bf16x8 q0 = *(const bf16x8*)(base);
  bf16x8 q1 = *(const bf16x8*)(base + 8);
  bf16x8 k0 = *(const bf16x8*)(base + 1024);
  bf16x8 k1 = *(const bf16x8*)(base + 1032);
  bf16x8 v0 = *(const bf16x8*)(base + 2048);
  bf16x8 v1 = *(const bf16x8*)(base + 2056);

  const size_t orow = ((size_t)bh * 2048 + t0 + r) * 64 + c;
  *(bf16x8*)(Qb + orow) = q0;
  *(bf16x8*)(Qb + orow + 8) = q1;
  *(bf16x8*)(Kb + orow) = k0;
  *(bf16x8*)(Kb + orow + 8) = k1;

  float* pk = pres + (((size_t)(b * 16 + h)) * 2048 + t0 + r) * 64 + c;
  float* pv = pk + (size_t)2 * 16 * 2048 * 64;
#pragma unroll
  for (int i = 0; i < 4; ++i) {
    float4 fk = {(float)k0[i * 4 + 0], (float)k0[i * 4 + 1],
                 (float)k0[i * 4 + 2], (float)k0[i * 4 + 3]};
    float4 fv = {(float)v0[i * 4 + 0], (float)v0[i * 4 + 1],
                 (float)v0[i * 4 + 2], (float)v0[i * 4 + 3]};
    if (i >= 2) {
      fk = {(float)k1[i * 4 - 8], (float)k1[i * 4 - 7], (float)k1[i * 4 - 6],
            (float)k1[i * 4 - 5]};
      fv = {(float)v1[i * 4 - 8], (float)v1[i * 4 - 7], (float)v1[i * 4 - 6],
            (float)v1[i * 4 - 5]};
    }
    ((float4*)pk)[i] = fk;
    ((float4*)pv)[i] = fv;
  }

  *(bf16x8*)(Vs + r * 72 + c) = v0;
  *(bf16x8*)(Vs + r * 72 + c + 8) = v1;
  __syncthreads();
  const int d = tid >> 2, tc = (tid & 3) * 16;
  bf16x8 o0, o1;
#pragma unroll
  for (int i = 0; i < 8; ++i) {
    o0[i] = Vs[(tc + i) * 72 + d];
    o1[i] = Vs[(tc + 8 + i) * 72 + d];
  }
  __bf16* vo = Vtb + ((size_t)bh * 64 + d) * 2048 + t0 + tc;
  *(bf16x8*)(vo) = o0;
  *(bf16x8*)(vo + 8) = o1;
}

// ---------------------------------------------------------------------------
// Flash attention, S^T layout (q on l15 -> lane-local online softmax).
// Block: paired q-tiles (qt, 31-qt); K-tiles of 64; entropy H = m+ln l - r/l.
// XCD swizzle: 4 bh per XCD (K/V L2 reuse across the 16 qp blocks of a bh).
// ---------------------------------------------------------------------------
__global__ __launch_bounds__(256) void attn_kernel(
    const __bf16* __restrict__ Qb, const __bf16* __restrict__ Kb,
    const __bf16* __restrict__ Vtb, __bf16* __restrict__ attn_out,
    float* __restrict__ ent_acc) {
  const int jlin = blockIdx.y * 16 + blockIdx.x;
  const int xcd = jlin & 7, u = jlin >> 3;
  const int qp = u & 15;           // pair index 0..15
  const int bh = xcd * 4 + (u >> 4);  // 0..31
  const int b = bh >> 4, h = bh & 15;
  const int tid = threadIdx.x, w = tid >> 6, lane = tid & 63;
  const int l15 = lane & 15, quad = lane >> 4;

  __shared__ __bf16 Ks[64 * 72];
  __shared__ __bf16 Vt[64 * 72];
  __shared__ __bf16 Ps[64 * 72];
  __shared__ float entred[4];

  const __bf16* qbase = Qb + (size_t)bh * 2048 * 64;
  const __bf16* kbase = Kb + (size_t)bh * 2048 * 64;
  const __bf16* vbase = Vtb + (size_t)bh * 64 * 2048;

  const int sr = tid >> 2, sc = (tid & 3) * 16;

  float hacc = 0.f;

#pragma unroll 1
  for (int ph = 0; ph < 2; ++ph) {
    const int qt = ph ? (31 - qp) : qp;
    const int q0 = qt * 64;
    const int qrow = q0 + w * 16 + l15;
    bf16x8 qf[2];
#pragma unroll
    for (int s = 0; s < 2; ++s)
      qf[s] = *(const bf16x8*)(qbase + (size_t)qrow * 64 + s * 32 + quad * 8);

    f32x4 O[4] = {};
    float m_s = -1e30f, l_s = 0.f, r_s = 0.f;

    for (int kt = 0; kt <= qt; ++kt) {
      const int kk0 = kt * 64;
      __syncthreads();
      {
        bf16x8 k0 = *(const bf16x8*)(kbase + (size_t)(kk0 + sr) * 64 + sc);
        bf16x8 k1 = *(const bf16x8*)(kbase + (size_t)(kk0 + sr) * 64 + sc + 8);
        bf16x8 v0 = *(const bf16x8*)(vbase + (size_t)sr * 2048 + kk0 + sc);
        bf16x8 v1 = *(const bf16x8*)(vbase + (size_t)sr * 2048 + kk0 + sc + 8);
        *(bf16x8*)(Ks + sr * 72 + sc) = k0;
        *(bf16x8*)(Ks + sr * 72 + sc + 8) = k1;
        *(bf16x8*)(Vt + sr * 72 + sc) = v0;
        *(bf16x8*)(Vt + sr * 72 + sc + 8) = v1;
      }
      __syncthreads();

      f32x4 sacc[4] = {};
#pragma unroll
      for (int s = 0; s < 2; ++s)
#pragma unroll
        for (int jt = 0; jt < 4; ++jt) {
          bf16x8 kf =
              *(const bf16x8*)(Ks + (jt * 16 + l15) * 72 + s * 32 + quad * 8);
          sacc[jt] =
              __builtin_amdgcn_mfma_f32_16x16x32_bf16(kf, qf[s], sacc[jt], 0, 0, 0);
        }

      float sv[4][4], ev[4][4];
#pragma unroll
      for (int jt = 0; jt < 4; ++jt)
#pragma unroll
        for (int r = 0; r < 4; ++r) {
          float xv = sacc[jt][r] * 0.125f;
          if (kk0 + jt * 16 + quad * 4 + r > qrow) xv = -1e30f;
          sv[jt][r] = xv;
        }
      float mx = sv[0][0];
#pragma unroll
      for (int jt = 0; jt < 4; ++jt)
#pragma unroll
        for (int r = 0; r < 4; ++r) mx = fmaxf(mx, sv[jt][r]);
      mx = fmaxf(mx, __shfl_xor(mx, 16, 64));
      mx = fmaxf(mx, __shfl_xor(mx, 32, 64));
      const float mn = fmaxf(m_s, mx);
      const float al = __expf(m_s - mn);
      m_s = mn;
      float ls = 0.f, rs2 = 0.f;
#pragma unroll
      for (int jt = 0; jt < 4; ++jt)
#pragma unroll
        for (int r = 0; r < 4; ++r) {
          const float e = __expf(sv[jt][r] - mn);
          ev[jt][r] = e;
          ls += e;
          rs2 = fmaf(e, sv[jt][r], rs2);
        }
      ls += __shfl_xor(ls, 16, 64);
      rs2 += __shfl_xor(rs2, 16, 64);
      ls += __shfl_xor(ls, 32, 64);
      rs2 += __shfl_xor(rs2, 32, 64);
      l_s = l_s * al + ls;
      r_s = r_s * al + rs2;
#pragma unroll
      for (int jt = 0; jt < 4; ++jt)
#pragma unroll
        for (int r = 0; r < 4; ++r) O[jt][r] *= al;

      __bf16* prow = Ps + (w * 16 + l15) * 72;
#pragma unroll
      for (int jt = 0; jt < 4; ++jt) {
        bf16x4 pk = {(__bf16)ev[jt][0], (__bf16)ev[jt][1], (__bf16)ev[jt][2],
                     (__bf16)ev[jt][3]};
        *(bf16x4*)(prow + jt * 16 + quad * 4) = pk;
      }
      asm volatile("s_waitcnt lgkmcnt(0)" ::: "memory");
#pragma unroll
      for (int s = 0; s < 2; ++s) {
        bf16x8 pf = *(const bf16x8*)(prow + s * 32 + quad * 8);
#pragma unroll
        for (int jt = 0; jt < 4; ++jt) {
          bf16x8 vf =
              *(const bf16x8*)(Vt + (jt * 16 + l15) * 72 + s * 32 + quad * 8);
          O[jt] = __builtin_amdgcn_mfma_f32_16x16x32_bf16(vf, pf, O[jt], 0, 0, 0);
        }
      }
    }

    const float inv = 1.0f / l_s;
    __bf16* obase = attn_out + (size_t)(b * 2048 + qrow) * 1024 + h * 64;
#pragma unroll
    for (int jt = 0; jt < 4; ++jt) {
      bf16x4 ov = {(__bf16)(O[jt][0] * inv), (__bf16)(O[jt][1] * inv),
                   (__bf16)(O[jt][2] * inv), (__bf16)(O[jt][3] * inv)};
      *(bf16x4*)(obase + jt * 16 + quad * 4) = ov;
    }
    hacc += m_s + __logf(l_s) - r_s * inv;  // replicated x4 across quads
  }

#pragma unroll
  for (int m = 1; m < 64; m <<= 1) hacc += __shfl_xor(hacc, m, 64);
  if (lane == 0) entred[w] = hacc;
  __syncthreads();
  if (tid == 0)
    atomicAdd(ent_acc, (entred[0] + entred[1] + entred[2] + entred[3]) *
                           (1.0f / (4.0f * 65536.0f)));
}

__global__ void ent_final(const float* __restrict__ e, float* __restrict__ o) {
  if (threadIdx.x == 0) o[0] = e[0];
}

// ---------------------------------------------------------------------------
extern "C" void kernel_launch(void* const* d_in, const int* in_sizes, int n_in,
                              void* d_out, int out_size, void* d_ws,
                              size_t ws_size, hipStream_t stream) {
  const float* x      = (const float*)d_in[0];
  const float* ln1_w  = (const float*)d_in[1];
  const float* ln1_b  = (const float*)d_in[2];
  const float* w_attn = (const float*)d_in[3];
  const float* b_attn = (const float*)d_in[4];
  const float* w_proj = (const float*)d_in[5];
  const float* b_proj = (const float*)d_in[6];
  const float* ln2_w  = (const float*)d_in[7];
  const float* ln2_b  = (const float*)d_in[8];
  const float* w_fc   = (const float*)d_in[9];
  const float* b_fc   = (const float*)d_in[10];
  const float* w_mlp  = (const float*)d_in[11];
  const float* b_mlp  = (const float*)d_in[12];

  char* ws = (char*)d_ws;
  constexpr size_t MB = 1024ull * 1024ull;
  __bf16* qkv    = (__bf16*)(ws + 0);
  __bf16* act    = (__bf16*)(ws + 0);
  __bf16* wbattn = (__bf16*)(ws + 24 * MB);
  __bf16* wbproj = (__bf16*)(ws + 30 * MB);
  __bf16* attnb  = (__bf16*)(ws + 32 * MB);
  __bf16* hb     = (__bf16*)(ws + 40 * MB);
  __bf16* Vtb    = (__bf16*)(ws + 40 * MB);
  __bf16* Qb     = (__bf16*)(ws + 48 * MB);
  __bf16* Kb     = (__bf16*)(ws + 56 * MB);
  float*  x2     = (float*)(ws + 48 * MB);
  __bf16* wbfc   = (__bf16*)(ws + 64 * MB);
  __bf16* wbmlp  = (__bf16*)(ws + 72 * MB);
  float*  entw   = (float*)(ws + 80 * MB);

  float* xout   = (float*)d_out;
  float* entout = xout + 4194304;
  float* pres   = xout + 4194305;

  hipMemsetAsync(entw, 0, sizeof(float), stream);
  cast_w<<<dim3(4096, 4), 256, 0, stream>>>(
      w_attn, w_proj, w_fc, w_mlp, wbattn, wbproj, wbfc, wbmlp,
      3 * 1024 * 1024, 1024 * 1024, 4 * 1024 * 1024, 4 * 1024 * 1024);
  ln_kernel<<<4096, 256, 0, stream>>>(x, ln1_w, ln1_b, hb);
  gemm_bt<0, 128, 4><<<dim3(24, 32), 256, 0, stream>>>(
      hb, wbattn, b_attn, nullptr, nullptr, qkv, 4096, 3072, 1024);
  prep_kernel<<<dim3(32, 32), 256, 0, stream>>>(qkv, Qb, Kb, Vtb, pres);
  attn_kernel<<<dim3(16, 32), 256, 0, stream>>>(Qb, Kb, Vtb, attnb, entw);
  gemm_bt<1, 64, 2><<<dim3(16, 32), 256, 0, stream>>>(
      attnb, wbproj, b_proj, x, x2, nullptr, 4096, 1024, 1024);
  ln_kernel<<<4096, 256, 0, stream>>>(x2, ln2_w, ln2_b, hb);
  gemm_bt<2, 128, 4><<<dim3(32, 32), 256, 0, stream>>>(
      hb, wbfc, b_fc, nullptr, nullptr, act, 4096, 4096, 1024);
  gemm_bt<1, 64, 2><<<dim3(16, 32), 256, 0, stream>>>(
      act, wbmlp, b_mlp, x2, xout, nullptr, 4096, 1024, 4096);
  ent_final<<<1, 64, 0, stream>>>(entw, entout);
}